// Round 5
// baseline (641.704 us; speedup 1.0000x reference)
//
#include <hip/hip_runtime.h>
#include <math.h>

#define NCLS 31
#define B 4096
#define D 512
#define N 8192
#define BT 128
#define NT (N / BT)               // 64 tiles per dim
#define NBLK (NT * (NT + 1) / 2)  // 2080 upper-tri tiles
#define BKB 64                    // bf16 K-chunk per iteration
#define NITER 24                  // K=1536 effective (hi|lo|hi vs hi|hi|lo)
#define NPB 694                   // persistent blocks (<= 256 CU * 3/CU = 768)

// ws float-index layout (memset zeroes first 24576 bytes = 6144 floats)
#define WS_SUMSQB 0      // 8 bucketed sumsq accumulators
#define WS_NBT    9
#define WS_SL     10
#define WS_CNT    11     // int done-counter
#define WS_BAR1   12     // int barrier 1
#define WS_BAR2   13     // int barrier 2
#define WS_HIST   16     // 31 ints
#define WS_PRES   47     // unsigned mask
#define WS_CSUM   48     // 31 floats
#define WS_SVAL   80     // 32
#define WS_TVAL   112    // 32
#define WS_ACCB   256    // 64 buckets, stride 16 floats (one cache line each)
#define WS_COLP   1280   // 8*512 bucketed column-sum partials (ends 5376)
#define WS_SQ     5376   // 8192 row squared norms (written, not memset)
#define WS_XC_BYTES 65536  // Xc: bf16 [8192][1024] (hi|lo), 16 MB

typedef __attribute__((ext_vector_type(8))) short bf16x8;
typedef __attribute__((ext_vector_type(4))) float f32x4;
typedef __attribute__((ext_vector_type(8))) unsigned short u16x8;

__device__ __forceinline__ unsigned short f2bf(float x) {
  unsigned u = __float_as_uint(x);
  u += 0x7fffu + ((u >> 16) & 1u);  // RNE (inputs finite)
  return (unsigned short)(u >> 16);
}
__device__ __forceinline__ float bf2f(unsigned short b) {
  return __uint_as_float(((unsigned)b) << 16);
}

__device__ __forceinline__ void async_lds16(const unsigned short* g, const short* l) {
  __builtin_amdgcn_global_load_lds(
      (const __attribute__((address_space(1))) unsigned int*)g,
      (__attribute__((address_space(3))) unsigned int*)l, 16, 0, 0);
}

// XOR-swizzled fragment read: logical (row r, 8-elem granule g) -> 16B
__device__ __forceinline__ bf16x8 frag_read(const short* tile, int r, int g) {
  int phys = r * 8 + (g ^ (r & 7));
  return *(const bf16x8*)(tile + phys * 8);
}

// device-scope arrive-and-spin barrier (all NPB blocks co-resident by launch_bounds)
__device__ __forceinline__ void gbar(int* cnt, int target) {
  __syncthreads();
  if (threadIdx.x == 0) {
    __threadfence();  // flush plain stores (cross-XCD L2 writeback)
    __hip_atomic_fetch_add(cnt, 1, __ATOMIC_ACQ_REL, __HIP_MEMORY_SCOPE_AGENT);
    while (__hip_atomic_load(cnt, __ATOMIC_ACQUIRE, __HIP_MEMORY_SCOPE_AGENT) < target)
      __builtin_amdgcn_s_sleep(2);
    __threadfence();  // acquire: invalidate stale lines before phase reads
  }
  __syncthreads();
}

__launch_bounds__(256, 3)
__global__ void k_mega(const float* __restrict__ src, const float* __restrict__ tgt,
                       const int* __restrict__ label, const float* __restrict__ logits,
                       const int* __restrict__ iter_p, float* __restrict__ wsf,
                       unsigned short* __restrict__ Xc, float* __restrict__ out) {
  __shared__ __align__(16) short tileA[BT * BKB];   // 16 KB, XOR-swizzled
  __shared__ __align__(16) short tileB[BT * BKB];   // 16 KB
  __shared__ float sqi[BT], sqj[BT];
  __shared__ float red[4];
  __shared__ float ssq[4];
  __shared__ int lcnt[32];
  __shared__ float lcsum[32];
  __shared__ unsigned lpres;

  const int tid = threadIdx.x, w = tid >> 6, lane = tid & 63;
  const int bidx = blockIdx.x;

  // ---------------- phase 1: convert + row sumsq + colsum + class stats ----------
  float (*rowbuf)[512] = (float(*)[512])tileA;   // alias 8 KB of tileA
  for (int u = bidx; u < N / 4; u += NPB) {
    __syncthreads();   // protect rowbuf reuse across iterations
    const bool statu = (u < 64);
    if (statu && tid < 32) { lcnt[tid] = 0; lcsum[tid] = 0.f; if (tid == 0) lpres = 0u; }
    const int row = u * 4 + w;
    const float* p = (row < B) ? src + (size_t)row * D : tgt + (size_t)(row - B) * D;
    float4 a = ((const float4*)p)[lane], b = ((const float4*)p)[lane + 64];
    ushort4 ha, la, hb, lb;
    ha.x = f2bf(a.x); la.x = f2bf(a.x - bf2f(ha.x));
    ha.y = f2bf(a.y); la.y = f2bf(a.y - bf2f(ha.y));
    ha.z = f2bf(a.z); la.z = f2bf(a.z - bf2f(ha.z));
    ha.w = f2bf(a.w); la.w = f2bf(a.w - bf2f(ha.w));
    hb.x = f2bf(b.x); lb.x = f2bf(b.x - bf2f(hb.x));
    hb.y = f2bf(b.y); lb.y = f2bf(b.y - bf2f(hb.y));
    hb.z = f2bf(b.z); lb.z = f2bf(b.z - bf2f(hb.z));
    hb.w = f2bf(b.w); lb.w = f2bf(b.w - bf2f(hb.w));
    size_t rb8 = (size_t)row * 1024;
    *(ushort4*)(Xc + rb8 + lane * 4)       = ha;   // hi cols 0..255
    *(ushort4*)(Xc + rb8 + 256 + lane * 4) = hb;   // hi cols 256..511
    *(ushort4*)(Xc + rb8 + 512 + lane * 4) = la;   // lo cols 0..255
    *(ushort4*)(Xc + rb8 + 768 + lane * 4) = lb;   // lo cols 256..511
    float s = a.x*a.x + a.y*a.y + a.z*a.z + a.w*a.w
            + b.x*b.x + b.y*b.y + b.z*b.z + b.w*b.w;
    *(float4*)&rowbuf[w][lane * 4] = a;
    *(float4*)&rowbuf[w][256 + lane * 4] = b;
    #pragma unroll
    for (int off = 32; off; off >>= 1) s += __shfl_down(s, off);
    if (lane == 0) { wsf[WS_SQ + row] = s; ssq[w] = s; }
    __syncthreads();
    float c0 = rowbuf[0][tid] + rowbuf[1][tid] + rowbuf[2][tid] + rowbuf[3][tid];
    float c1 = rowbuf[0][tid+256] + rowbuf[1][tid+256] + rowbuf[2][tid+256] + rowbuf[3][tid+256];
    int bkt = (u & 7) * 512;
    atomicAdd(&wsf[WS_COLP + bkt + tid], c0);
    atomicAdd(&wsf[WS_COLP + bkt + tid + 256], c1);
    if (tid == 0)
      atomicAdd(&wsf[WS_SUMSQB + (u & 7)], ssq[0] + ssq[1] + ssq[2] + ssq[3]);
    if (statu) {
      if (tid < 64) {
        int r = u * 64 + tid;
        atomicAdd(&lcnt[label[r]], 1);
        const float* lp = logits + (size_t)r * NCLS;
        float mx = -1e30f; int am = 0;
        #pragma unroll
        for (int c = 0; c < NCLS; c++) {
          float v = lp[c];
          atomicAdd(&lcsum[c], v);
          if (v > mx) { mx = v; am = c; }  // strict >: first max, matches argmax
        }
        atomicOr(&lpres, 1u << am);
      }
      __syncthreads();
      if (tid < NCLS) {
        if (lcnt[tid]) atomicAdd((int*)&wsf[WS_HIST] + tid, lcnt[tid]);
        atomicAdd(&wsf[WS_CSUM + tid], lcsum[tid]);
      }
      if (tid == 0) atomicOr((unsigned*)&wsf[WS_PRES], lpres);
    }
  }
  gbar((int*)&wsf[WS_BAR1], NPB);

  // ---------------- phase 2: block 0 finalizes stats -----------------------------
  if (bidx == 0) {
    float v = 0.f;
    for (int c = tid; c < 512; c += 256) {
      float t = 0.f;
      #pragma unroll
      for (int bk = 0; bk < 8; bk++) t += wsf[WS_COLP + bk * 512 + c];
      v += t * t;
    }
    #pragma unroll
    for (int off = 32; off; off >>= 1) v += __shfl_down(v, off);
    if (lane == 0) red[w] = v;
    __syncthreads();
    if (tid == 0) {
      unsigned presT = *(unsigned*)&wsf[WS_PRES];
      int cm = 0;
      for (int c = 0; c < NCLS; c++) {
        int cnt = ((int*)&wsf[WS_HIST])[c];
        bool m = (cnt > 0) && ((presT >> c) & 1u);
        if (m) cm++;
        wsf[WS_SVAL + c] = m ? 1.f / (float)cnt : 0.f;
        float cs = wsf[WS_CSUM + c]; if (cs == 0.f) cs = 100.f;
        wsf[WS_TVAL + c] = m ? -1.f / cs : 0.f;
      }
      wsf[WS_SVAL + 31] = 0.f; wsf[WS_TVAL + 31] = 0.f;
      float scale = (cm > 0) ? 1.f / (float)cm : 0.f;
      float pp = (float)iter_p[0] / 1000.f;
      float lamb = 2.f / (1.f + __expf(-pp)) - 1.f;
      wsf[WS_SL] = scale * lamb;
      double colnorm2 = (double)red[0] + red[1] + red[2] + red[3];
      double sumsq = 0.0;
      for (int bk = 0; bk < 8; bk++) sumsq += (double)wsf[WS_SUMSQB + bk];
      double sumL2 = 2.0 * (double)N * sumsq - 2.0 * colnorm2;
      wsf[WS_NBT] = (float)(-((double)N * (double)N - (double)N) / (4.0 * sumL2));
    }
  }
  gbar((int*)&wsf[WS_BAR2], NPB);

  // ---------------- phase 3: tile loop (R2-proven K-loop structure) --------------
  const int woff_m = (w >> 1) * 64, woff_n = (w & 1) * 64;
  const int fr = lane & 15, fg = lane >> 4;
  const int srow = lane >> 3;
  const int sgrp = (lane & 7) ^ srow;
  const float nbt = wsf[WS_NBT];
  float part = 0.f;

  for (int t = bidx; t < NBLK; t += NPB) {
    // triangular decode: bi <= bj, S(bi) = bi*(129-bi)/2
    int bid = t;
    int bi = (int)(64.5f - sqrtf(64.5f * 64.5f - 2.0f * (float)bid));
    while (bi > 0 && bid < (bi * (129 - bi)) / 2) --bi;
    while (bid >= ((bi + 1) * (128 - bi)) / 2) ++bi;
    int bj = bi + (bid - (bi * (129 - bi)) / 2);
    const int i0 = bi * BT, j0 = bj * BT;
    const float mult = (bi == bj) ? 1.f : 2.f;

    if (tid < 128) sqi[tid] = wsf[WS_SQ + i0 + tid];
    else           sqj[tid - 128] = wsf[WS_SQ + j0 + (tid - 128)];

    f32x4 acc[4][4];
    #pragma unroll
    for (int mt = 0; mt < 4; mt++)
      #pragma unroll
      for (int nt = 0; nt < 4; nt++) acc[mt][nt] = (f32x4){0.f, 0.f, 0.f, 0.f};

    for (int it = 0; it < NITER; ++it) {
      // segment remap: A' = [hi|lo|hi], B' = [hi|hi|lo] over Xc rows [hi(512)|lo(512)]
      const int offA = (it < 16 ? it : it - 16) * BKB;
      const int offB = (it < 8 ? it : it - 8) * BKB;
      __syncthreads();
      #pragma unroll
      for (int q = 0; q < 4; ++q) {
        const int inst = w * 4 + q;
        const int rl = inst * 8 + srow;
        async_lds16(Xc + (size_t)(i0 + rl) * 1024 + offA + sgrp * 8,
                    tileA + inst * 512);
        async_lds16(Xc + (size_t)(j0 + rl) * 1024 + offB + sgrp * 8,
                    tileB + inst * 512);
      }
      __syncthreads();
      #pragma unroll
      for (int ks = 0; ks < 2; ++ks) {
        bf16x8 af[4], bfr[4];
        #pragma unroll
        for (int mt = 0; mt < 4; mt++)
          af[mt] = frag_read(tileA, woff_m + mt * 16 + fr, ks * 4 + fg);
        #pragma unroll
        for (int nt = 0; nt < 4; nt++)
          bfr[nt] = frag_read(tileB, woff_n + nt * 16 + fr, ks * 4 + fg);
        #pragma unroll
        for (int mt = 0; mt < 4; mt++)
          #pragma unroll
          for (int nt = 0; nt < 4; nt++)
            acc[mt][nt] = __builtin_amdgcn_mfma_f32_16x16x32_bf16(
                af[mt], bfr[nt], acc[mt][nt], 0, 0, 0);
      }
    }

    // acc -> multi-band Gaussian kernel: t + t^2 + t^4 + t^8 + t^16
    float sj4[4], si16[4][4];
    #pragma unroll
    for (int nt = 0; nt < 4; nt++) sj4[nt] = sqj[woff_n + nt * 16 + fr];
    #pragma unroll
    for (int mt = 0; mt < 4; mt++)
      #pragma unroll
      for (int tt = 0; tt < 4; tt++) si16[mt][tt] = sqi[woff_m + mt * 16 + fg * 4 + tt];
    #pragma unroll
    for (int mt = 0; mt < 4; mt++)
      #pragma unroll
      for (int nt = 0; nt < 4; nt++)
        #pragma unroll
        for (int tt = 0; tt < 4; tt++) {
          float d2 = fmaxf(si16[mt][tt] + sj4[nt] - 2.f * acc[mt][nt][tt], 0.f);
          float e1 = __expf(d2 * nbt);
          float e2 = e1 * e1, e4 = e2 * e2, e8 = e4 * e4, e16 = e8 * e8;
          acc[mt][nt][tt] = ((e16 + e8) + (e4 + e2)) + e1;
        }

    // build Q tiles (hi|lo bf16) into reused LDS, same swizzle
    __syncthreads();
    {
      const int tq = tid & 127;
      short* qt = (tid < 128) ? tileA : tileB;
      const int gq = ((tid < 128) ? i0 : j0) + tq;
      const int lab = (gq < B) ? label[gq] : -1;
      const float sv = (gq < B) ? wsf[WS_SVAL + lab] : 0.f;
      const float* lp = (gq < B) ? (const float*)0 : logits + (size_t)(gq - B) * NCLS;
      #pragma unroll
      for (int g = 0; g < 8; ++g) {
        u16x8 pack = (u16x8){0,0,0,0,0,0,0,0};
        const int cbase = (g & 3) * 8;
        if (gq < B) {
          if (lab >= cbase && lab < cbase + 8) {
            unsigned short h = f2bf(sv);
            pack[lab - cbase] = (g < 4) ? h : f2bf(sv - bf2f(h));
          }
        } else {
          #pragma unroll
          for (int jc = 0; jc < 8; ++jc) {
            int cc = cbase + jc;
            if (cc < NCLS) {
              float vq = lp[cc] * wsf[WS_TVAL + cc];
              unsigned short h = f2bf(vq);
              pack[jc] = (g < 4) ? h : f2bf(vq - bf2f(h));
            }
          }
        }
        int phys = tq * 8 + (g ^ (tq & 7));
        *(u16x8*)(qt + phys * 8) = pack;
      }
    }
    __syncthreads();

    // Gram via MFMA (K=96: hi.hi + lo.hi + hi.lo), elementwise-dot with kernel values
    float tp = 0.f;
    #pragma unroll
    for (int ch = 0; ch < 3; ++ch) {
      const int ab = (ch == 1) ? 4 : 0, bb = (ch == 2) ? 4 : 0;
      bf16x8 af[4], bfr[4];
      #pragma unroll
      for (int mt = 0; mt < 4; mt++)
        af[mt] = frag_read(tileA, woff_m + mt * 16 + fr, ab + fg);
      #pragma unroll
      for (int nt = 0; nt < 4; nt++)
        bfr[nt] = frag_read(tileB, woff_n + nt * 16 + fr, bb + fg);
      #pragma unroll
      for (int mt = 0; mt < 4; mt++)
        #pragma unroll
        for (int nt = 0; nt < 4; nt++) {
          f32x4 z = (f32x4){0.f, 0.f, 0.f, 0.f};
          f32x4 g = __builtin_amdgcn_mfma_f32_16x16x32_bf16(af[mt], bfr[nt], z, 0, 0, 0);
          tp += acc[mt][nt].x * g.x + acc[mt][nt].y * g.y
              + acc[mt][nt].z * g.z + acc[mt][nt].w * g.w;
        }
    }
    part += tp * mult;
  }

  // block reduction once, bucketed atomic, done-counter
  #pragma unroll
  for (int off = 32; off; off >>= 1) part += __shfl_down(part, off);
  __syncthreads();
  if (lane == 0) red[w] = part;
  __syncthreads();
  if (tid == 0) {
    float blocksum = red[0] + red[1] + red[2] + red[3];
    atomicAdd(&wsf[WS_ACCB + (bidx & 63) * 16], blocksum);
    int old = __hip_atomic_fetch_add((int*)&wsf[WS_CNT], 1,
                                     __ATOMIC_ACQ_REL, __HIP_MEMORY_SCOPE_AGENT);
    if (old == NPB - 1) {
      float total = 0.f;
      for (int k = 0; k < 64; ++k)
        total += __hip_atomic_load(&wsf[WS_ACCB + k * 16],
                                   __ATOMIC_ACQUIRE, __HIP_MEMORY_SCOPE_AGENT);
      out[0] = total * wsf[WS_SL];
    }
  }
}

extern "C" void kernel_launch(void* const* d_in, const int* in_sizes, int n_in,
                              void* d_out, int out_size, void* d_ws, size_t ws_size,
                              hipStream_t stream) {
  const float* src    = (const float*)d_in[0];
  const float* tgt    = (const float*)d_in[1];
  const int*   label  = (const int*)d_in[2];
  const float* logits = (const float*)d_in[3];
  const int*   iter_p = (const int*)d_in[4];
  float* wsf = (float*)d_ws;
  unsigned short* Xc = (unsigned short*)((char*)d_ws + WS_XC_BYTES);
  float* out = (float*)d_out;

  hipMemsetAsync(d_ws, 0, 24576, stream);   // zero scalars/barriers/buckets/stats
  k_mega<<<NPB, 256, 0, stream>>>(src, tgt, label, logits, iter_p, wsf, Xc, out);
}

// Round 6
// 336.469 us; speedup vs baseline: 1.9072x; 1.9072x over previous
//
#include <hip/hip_runtime.h>
#include <math.h>

#define NCLS 31
#define B 4096
#define D 512
#define N 8192
#define BT 128
#define NT (N / BT)               // 64 tiles per dim
#define NBLK (NT * (NT + 1) / 2)  // 2080 upper-tri tiles
#define BKB 64                    // bf16 K-chunk per iteration
#define NITER 24                  // K=1536 effective (hi|lo|hi vs hi|hi|lo)
#define NPRE 512                  // k_pre blocks (16 rows each)

// ws float-index layout (memset zeroes first 24576 B = 6144 floats)
#define WS_SUMSQB 0      // 8 bucketed sumsq accumulators
#define WS_NBT    9
#define WS_SL     10
#define WS_CNT    11     // int done-counter (k_main)
#define WS_CNT2   12     // int done-counter (k_pre)
#define WS_HIST   16     // 31 ints
#define WS_PRES   47     // unsigned mask
#define WS_CSUM   48     // 31 floats
#define WS_SVAL   80     // 32
#define WS_TVAL   112    // 32
#define WS_ACCB   256    // 64 buckets, stride 16 floats (one line each)
#define WS_COLP   1280   // 8*512 bucketed column-sum partials (ends 5376)
#define WS_SQ     5376   // 8192 row squared norms (fully written by k_pre)
#define WS_XC_BYTES 65536  // Xc: bf16 [8192][1024] (hi|lo), 16 MB

typedef __attribute__((ext_vector_type(8))) short bf16x8;
typedef __attribute__((ext_vector_type(4))) float f32x4;
typedef __attribute__((ext_vector_type(8))) unsigned short u16x8;

__device__ __forceinline__ unsigned short f2bf(float x) {
  unsigned u = __float_as_uint(x);
  u += 0x7fffu + ((u >> 16) & 1u);  // RNE (inputs finite)
  return (unsigned short)(u >> 16);
}
__device__ __forceinline__ float bf2f(unsigned short b) {
  return __uint_as_float(((unsigned)b) << 16);
}

__device__ __forceinline__ void async_lds16(const unsigned short* g, const short* l) {
  __builtin_amdgcn_global_load_lds(
      (const __attribute__((address_space(1))) unsigned int*)g,
      (__attribute__((address_space(3))) unsigned int*)l, 16, 0, 0);
}

// XOR-swizzled fragment read: logical (row r, 8-elem granule g) -> 16B
__device__ __forceinline__ bf16x8 frag_read(const short* tile, int r, int g) {
  int phys = r * 8 + (g ^ (r & 7));
  return *(const bf16x8*)(tile + phys * 8);
}

// k_pre: convert + row sumsq + colsum (register-accumulated, one bucketed atomic
// set per block) + class stats; LAST block (done-counter) finalizes all stats.
__global__ void k_pre(const float* __restrict__ src, const float* __restrict__ tgt,
                      const int* __restrict__ label, const float* __restrict__ logits,
                      const int* __restrict__ iter_p, float* __restrict__ wsf,
                      unsigned short* __restrict__ Xc) {
  __shared__ float rowbuf[4][512];
  __shared__ float ssq[4];
  __shared__ int lcnt[32];
  __shared__ float lcsum[32];
  __shared__ unsigned lpres;
  __shared__ float red_[4];
  __shared__ int lastblk;
  const int tid = threadIdx.x, w = tid >> 6, lane = tid & 63;
  const int b = blockIdx.x;
  if (tid < 32) { lcnt[tid] = 0; lcsum[tid] = 0.f; }
  if (tid == 0) lpres = 0u;

  float c0acc = 0.f, c1acc = 0.f, ssqacc = 0.f;
  for (int g = 0; g < 4; ++g) {           // 4 row-groups of 4 rows = 16 rows/block
    const int row = (b * 4 + g) * 4 + w;
    const float* p = (row < B) ? src + (size_t)row * D : tgt + (size_t)(row - B) * D;
    float4 a = ((const float4*)p)[lane], bb = ((const float4*)p)[lane + 64];
    ushort4 ha, la, hb, lb;
    ha.x = f2bf(a.x); la.x = f2bf(a.x - bf2f(ha.x));
    ha.y = f2bf(a.y); la.y = f2bf(a.y - bf2f(ha.y));
    ha.z = f2bf(a.z); la.z = f2bf(a.z - bf2f(ha.z));
    ha.w = f2bf(a.w); la.w = f2bf(a.w - bf2f(ha.w));
    hb.x = f2bf(bb.x); lb.x = f2bf(bb.x - bf2f(hb.x));
    hb.y = f2bf(bb.y); lb.y = f2bf(bb.y - bf2f(hb.y));
    hb.z = f2bf(bb.z); lb.z = f2bf(bb.z - bf2f(hb.z));
    hb.w = f2bf(bb.w); lb.w = f2bf(bb.w - bf2f(hb.w));
    size_t rb8 = (size_t)row * 1024;
    *(ushort4*)(Xc + rb8 + lane * 4)       = ha;   // hi cols 0..255
    *(ushort4*)(Xc + rb8 + 256 + lane * 4) = hb;   // hi cols 256..511
    *(ushort4*)(Xc + rb8 + 512 + lane * 4) = la;   // lo cols 0..255
    *(ushort4*)(Xc + rb8 + 768 + lane * 4) = lb;   // lo cols 256..511
    float s = a.x*a.x + a.y*a.y + a.z*a.z + a.w*a.w
            + bb.x*bb.x + bb.y*bb.y + bb.z*bb.z + bb.w*bb.w;
    *(float4*)&rowbuf[w][lane * 4] = a;
    *(float4*)&rowbuf[w][256 + lane * 4] = bb;
    #pragma unroll
    for (int off = 32; off; off >>= 1) s += __shfl_down(s, off);
    if (lane == 0) { wsf[WS_SQ + row] = s; ssq[w] = s; }
    __syncthreads();
    c0acc += rowbuf[0][tid] + rowbuf[1][tid] + rowbuf[2][tid] + rowbuf[3][tid];
    c1acc += rowbuf[0][tid+256] + rowbuf[1][tid+256] + rowbuf[2][tid+256] + rowbuf[3][tid+256];
    if (tid == 0) ssqacc += ssq[0] + ssq[1] + ssq[2] + ssq[3];
    __syncthreads();
  }
  // class stats for this block's 16 rows
  {
    const int r0 = b * 16;
    if (r0 < B) {
      if (tid < 16) atomicAdd(&lcnt[label[r0 + tid]], 1);
      __syncthreads();
      if (tid < NCLS && lcnt[tid]) atomicAdd((int*)&wsf[WS_HIST] + tid, lcnt[tid]);
    } else {
      if (tid < 16) {
        const float* lp = logits + (size_t)(r0 - B + tid) * NCLS;
        float mx = -1e30f; int am = 0;
        #pragma unroll
        for (int c = 0; c < NCLS; c++) {
          float v = lp[c];
          atomicAdd(&lcsum[c], v);
          if (v > mx) { mx = v; am = c; }  // strict >: first max, matches argmax
        }
        atomicOr(&lpres, 1u << am);
      }
      __syncthreads();
      if (tid < NCLS) atomicAdd(&wsf[WS_CSUM + tid], lcsum[tid]);
      if (tid == 0) atomicOr((unsigned*)&wsf[WS_PRES], lpres);
    }
  }
  // one bucketed atomic set per block
  const int bkt = (b & 7) * 512;
  atomicAdd(&wsf[WS_COLP + bkt + tid], c0acc);
  atomicAdd(&wsf[WS_COLP + bkt + 256 + tid], c1acc);
  if (tid == 0) atomicAdd(&wsf[WS_SUMSQB + (b & 7)], ssqacc);

  // done-counter; last block finalizes stats
  __syncthreads();
  if (tid == 0)
    lastblk = (__hip_atomic_fetch_add((int*)&wsf[WS_CNT2], 1,
               __ATOMIC_RELEASE, __HIP_MEMORY_SCOPE_AGENT) == NPRE - 1);
  __syncthreads();
  if (!lastblk) return;
  __threadfence();  // acquire: see all blocks' atomics/stores
  float cs0 = 0.f, cs1 = 0.f;
  #pragma unroll
  for (int bk = 0; bk < 8; bk++) {
    cs0 += wsf[WS_COLP + bk * 512 + tid];
    cs1 += wsf[WS_COLP + bk * 512 + 256 + tid];
  }
  float v = cs0 * cs0 + cs1 * cs1;
  #pragma unroll
  for (int off = 32; off; off >>= 1) v += __shfl_down(v, off);
  if (lane == 0) red_[w] = v;
  __syncthreads();
  if (tid == 0) {
    unsigned presT = *(unsigned*)&wsf[WS_PRES];
    int cm = 0;
    for (int c = 0; c < NCLS; c++) {
      int cnt = ((int*)&wsf[WS_HIST])[c];
      bool m = (cnt > 0) && ((presT >> c) & 1u);
      if (m) cm++;
      wsf[WS_SVAL + c] = m ? 1.f / (float)cnt : 0.f;
      float cs = wsf[WS_CSUM + c]; if (cs == 0.f) cs = 100.f;
      wsf[WS_TVAL + c] = m ? -1.f / cs : 0.f;
    }
    wsf[WS_SVAL + 31] = 0.f; wsf[WS_TVAL + 31] = 0.f;
    float scale = (cm > 0) ? 1.f / (float)cm : 0.f;
    float pp = (float)iter_p[0] / 1000.f;
    float lamb = 2.f / (1.f + __expf(-pp)) - 1.f;
    wsf[WS_SL] = scale * lamb;
    double colnorm2 = (double)red_[0] + red_[1] + red_[2] + red_[3];
    double sumsq = 0.0;
    for (int bk = 0; bk < 8; bk++) sumsq += (double)wsf[WS_SUMSQB + bk];
    double sumL2 = 2.0 * (double)N * sumsq - 2.0 * colnorm2;
    wsf[WS_NBT] = (float)(-((double)N * (double)N - (double)N) / (4.0 * sumL2));
  }
}

// loss = sum_{tile} mult * K(d2) .* (Q_i Q_j^T), bf16 MFMA hi/lo (R2 structure)
__launch_bounds__(256, 4)
__global__ void k_main(const unsigned short* __restrict__ Xc,
                       const int* __restrict__ label, const float* __restrict__ logits,
                       float* __restrict__ wsf, float* __restrict__ out) {
  __shared__ __align__(16) short tileA[BT * BKB];   // 16 KB, XOR-swizzled
  __shared__ __align__(16) short tileB[BT * BKB];   // 16 KB
  __shared__ float sqi[BT], sqj[BT];
  __shared__ float red[4];

  // triangular block decode: bi <= bj, S(bi) = bi*(129-bi)/2
  int bid = blockIdx.x;
  int bi = (int)(64.5f - sqrtf(64.5f * 64.5f - 2.0f * (float)bid));
  while (bi > 0 && bid < (bi * (129 - bi)) / 2) --bi;
  while (bid >= ((bi + 1) * (128 - bi)) / 2) ++bi;
  int bj = bi + (bid - (bi * (129 - bi)) / 2);
  const int i0 = bi * BT, j0 = bj * BT;
  const float mult = (bi == bj) ? 1.f : 2.f;

  const int tid = threadIdx.x;
  const int w = tid >> 6, lane = tid & 63;
  const int woff_m = (w >> 1) * 64, woff_n = (w & 1) * 64;
  const int fr = lane & 15, fg = lane >> 4;       // fragment row / k-group
  const int srow = lane >> 3;                     // staging row-in-8
  const int sgrp = (lane & 7) ^ srow;             // staging logical granule

  if (tid < 128) sqi[tid] = wsf[WS_SQ + i0 + tid];
  else           sqj[tid - 128] = wsf[WS_SQ + j0 + (tid - 128)];
  const float nbt = wsf[WS_NBT];

  f32x4 acc[4][4];
  #pragma unroll
  for (int mt = 0; mt < 4; mt++)
    #pragma unroll
    for (int nt = 0; nt < 4; nt++) acc[mt][nt] = (f32x4){0.f, 0.f, 0.f, 0.f};

  for (int it = 0; it < NITER; ++it) {
    // segment remap: A' = [hi|lo|hi], B' = [hi|hi|lo] over Xc rows [hi(512)|lo(512)]
    const int offA = (it < 16 ? it : it - 16) * BKB;
    const int offB = (it < 8 ? it : it - 8) * BKB;
    __syncthreads();
    #pragma unroll
    for (int q = 0; q < 4; ++q) {
      const int inst = w * 4 + q;                  // 0..15, 8 rows each
      const int rl = inst * 8 + srow;              // local row 0..127
      async_lds16(Xc + (size_t)(i0 + rl) * 1024 + offA + sgrp * 8,
                  tileA + inst * 512);
      async_lds16(Xc + (size_t)(j0 + rl) * 1024 + offB + sgrp * 8,
                  tileB + inst * 512);
    }
    __syncthreads();
    #pragma unroll
    for (int ks = 0; ks < 2; ++ks) {
      bf16x8 af[4], bfr[4];
      #pragma unroll
      for (int mt = 0; mt < 4; mt++)
        af[mt] = frag_read(tileA, woff_m + mt * 16 + fr, ks * 4 + fg);
      #pragma unroll
      for (int nt = 0; nt < 4; nt++)
        bfr[nt] = frag_read(tileB, woff_n + nt * 16 + fr, ks * 4 + fg);
      #pragma unroll
      for (int mt = 0; mt < 4; mt++)
        #pragma unroll
        for (int nt = 0; nt < 4; nt++)
          acc[mt][nt] = __builtin_amdgcn_mfma_f32_16x16x32_bf16(
              af[mt], bfr[nt], acc[mt][nt], 0, 0, 0);
    }
  }

  // acc -> multi-band Gaussian kernel: t + t^2 + t^4 + t^8 + t^16
  float sj4[4], si16[4][4];
  #pragma unroll
  for (int nt = 0; nt < 4; nt++) sj4[nt] = sqj[woff_n + nt * 16 + fr];
  #pragma unroll
  for (int mt = 0; mt < 4; mt++)
    #pragma unroll
    for (int t = 0; t < 4; t++) si16[mt][t] = sqi[woff_m + mt * 16 + fg * 4 + t];
  #pragma unroll
  for (int mt = 0; mt < 4; mt++)
    #pragma unroll
    for (int nt = 0; nt < 4; nt++)
      #pragma unroll
      for (int t = 0; t < 4; t++) {
        float d2 = fmaxf(si16[mt][t] + sj4[nt] - 2.f * acc[mt][nt][t], 0.f);
        float e1 = __expf(d2 * nbt);
        float e2 = e1 * e1, e4 = e2 * e2, e8 = e4 * e4, e16 = e8 * e8;
        acc[mt][nt][t] = ((e16 + e8) + (e4 + e2)) + e1;
      }

  // build Q tiles (hi|lo bf16) into reused LDS, same swizzle
  __syncthreads();
  {
    const int t = tid & 127;
    short* qt = (tid < 128) ? tileA : tileB;
    const int gq = ((tid < 128) ? i0 : j0) + t;
    const int lab = (gq < B) ? label[gq] : -1;
    const float sv = (gq < B) ? wsf[WS_SVAL + lab] : 0.f;
    const float* lp = (gq < B) ? (const float*)0 : logits + (size_t)(gq - B) * NCLS;
    #pragma unroll
    for (int g = 0; g < 8; ++g) {
      u16x8 pack = (u16x8){0,0,0,0,0,0,0,0};
      const int cbase = (g & 3) * 8;
      if (gq < B) {
        if (lab >= cbase && lab < cbase + 8) {
          unsigned short h = f2bf(sv);
          pack[lab - cbase] = (g < 4) ? h : f2bf(sv - bf2f(h));
        }
      } else {
        #pragma unroll
        for (int jc = 0; jc < 8; ++jc) {
          int cc = cbase + jc;
          if (cc < NCLS) {
            float vq = lp[cc] * wsf[WS_TVAL + cc];
            unsigned short h = f2bf(vq);
            pack[jc] = (g < 4) ? h : f2bf(vq - bf2f(h));
          }
        }
      }
      int phys = t * 8 + (g ^ (t & 7));
      *(u16x8*)(qt + phys * 8) = pack;
    }
  }
  __syncthreads();

  // Gram via MFMA (K=96: hi.hi + lo.hi + hi.lo), elementwise-dot with kernel values
  float part = 0.f;
  #pragma unroll
  for (int ch = 0; ch < 3; ++ch) {
    const int ab = (ch == 1) ? 4 : 0, bb = (ch == 2) ? 4 : 0;
    bf16x8 af[4], bfr[4];
    #pragma unroll
    for (int mt = 0; mt < 4; mt++)
      af[mt] = frag_read(tileA, woff_m + mt * 16 + fr, ab + fg);
    #pragma unroll
    for (int nt = 0; nt < 4; nt++)
      bfr[nt] = frag_read(tileB, woff_n + nt * 16 + fr, bb + fg);
    #pragma unroll
    for (int mt = 0; mt < 4; mt++)
      #pragma unroll
      for (int nt = 0; nt < 4; nt++) {
        f32x4 z = (f32x4){0.f, 0.f, 0.f, 0.f};
        f32x4 g = __builtin_amdgcn_mfma_f32_16x16x32_bf16(af[mt], bfr[nt], z, 0, 0, 0);
        part += acc[mt][nt].x * g.x + acc[mt][nt].y * g.y
              + acc[mt][nt].z * g.z + acc[mt][nt].w * g.w;
      }
  }
  part *= mult;
  #pragma unroll
  for (int off = 32; off; off >>= 1) part += __shfl_down(part, off);
  if (lane == 0) red[w] = part;
  __syncthreads();

  // wave-0 finalize: bucketed atomic + release counter; last block sums & writes out
  if (w == 0) {
    float bs = red[0] + red[1] + red[2] + red[3];
    if (lane == 0) atomicAdd(&wsf[WS_ACCB + (blockIdx.x & 63) * 16], bs);
    int old = 0;
    if (lane == 0)
      old = __hip_atomic_fetch_add((int*)&wsf[WS_CNT], 1,
                                   __ATOMIC_RELEASE, __HIP_MEMORY_SCOPE_AGENT);
    old = __shfl(old, 0);
    if (old == NBLK - 1) {
      __builtin_amdgcn_fence(__ATOMIC_ACQUIRE, "agent");
      float t = __hip_atomic_load(&wsf[WS_ACCB + lane * 16],
                                  __ATOMIC_RELAXED, __HIP_MEMORY_SCOPE_AGENT);
      #pragma unroll
      for (int off = 32; off; off >>= 1) t += __shfl_down(t, off);
      if (lane == 0) out[0] = t * wsf[WS_SL];
    }
  }
}

extern "C" void kernel_launch(void* const* d_in, const int* in_sizes, int n_in,
                              void* d_out, int out_size, void* d_ws, size_t ws_size,
                              hipStream_t stream) {
  const float* src    = (const float*)d_in[0];
  const float* tgt    = (const float*)d_in[1];
  const int*   label  = (const int*)d_in[2];
  const float* logits = (const float*)d_in[3];
  const int*   iter_p = (const int*)d_in[4];
  float* wsf = (float*)d_ws;
  unsigned short* Xc = (unsigned short*)((char*)d_ws + WS_XC_BYTES);
  float* out = (float*)d_out;

  hipMemsetAsync(d_ws, 0, 24576, stream);   // zero scalars/counters/buckets/stats
  k_pre<<<NPRE, 256, 0, stream>>>(src, tgt, label, logits, iter_p, wsf, Xc);
  k_main<<<NBLK, 256, 0, stream>>>(Xc, label, logits, wsf, out);
}

// Round 7
// 293.117 us; speedup vs baseline: 2.1892x; 1.1479x over previous
//
#include <hip/hip_runtime.h>
#include <math.h>

#define NCLS 31
#define B 4096
#define D 512
#define N 8192
#define BT 128
#define NT (N / BT)               // 64 tiles per dim
#define NBLK (NT * (NT + 1) / 2)  // 2080 upper-tri tiles
#define BKB 64                    // bf16 K-chunk per iteration
#define NITER 24                  // K=1536 effective (hi|lo|hi vs hi|hi|lo)
#define NPRE 512                  // k_pre blocks (16 rows each)

// ws float-index layout (memset zeroes first 24576 B = 6144 floats)
#define WS_SUMSQB 0      // 8 bucketed sumsq accumulators
#define WS_NBT    9
#define WS_SL     10
#define WS_CNT    11     // int done-counter (k_main)
#define WS_CNT2   12     // int done-counter (k_pre)
#define WS_HIST   16     // 31 ints
#define WS_PRES   47     // unsigned mask
#define WS_CSUM   48     // 31 floats
#define WS_SVAL   80     // 32
#define WS_TVAL   112    // 32
#define WS_ACCB   256    // 64 buckets, stride 16 floats (one line each)
#define WS_COLP   1280   // 8*512 bucketed column-sum partials (ends 5376)
#define WS_SQ     5376   // 8192 row squared norms (fully written by k_pre)
#define WS_XC_BYTES 65536  // Xc: bf16 [8192][1024] (hi|lo), 16 MB

typedef __attribute__((ext_vector_type(8))) short bf16x8;
typedef __attribute__((ext_vector_type(4))) float f32x4;
typedef __attribute__((ext_vector_type(8))) unsigned short u16x8;

__device__ __forceinline__ unsigned short f2bf(float x) {
  unsigned u = __float_as_uint(x);
  u += 0x7fffu + ((u >> 16) & 1u);  // RNE (inputs finite)
  return (unsigned short)(u >> 16);
}
__device__ __forceinline__ float bf2f(unsigned short b) {
  return __uint_as_float(((unsigned)b) << 16);
}

__device__ __forceinline__ void async_lds16(const unsigned short* g, const short* l) {
  __builtin_amdgcn_global_load_lds(
      (const __attribute__((address_space(1))) unsigned int*)g,
      (__attribute__((address_space(3))) unsigned int*)l, 16, 0, 0);
}

// XOR-swizzled fragment read: logical (row r, 8-elem granule g) -> 16B
__device__ __forceinline__ bf16x8 frag_read(const short* tile, int r, int g) {
  int phys = r * 8 + (g ^ (r & 7));
  return *(const bf16x8*)(tile + phys * 8);
}

// k_pre: convert + row sumsq + colsum (register-accumulated, one bucketed atomic
// set per block) + class stats; LAST block (done-counter) finalizes all stats.
__global__ void k_pre(const float* __restrict__ src, const float* __restrict__ tgt,
                      const int* __restrict__ label, const float* __restrict__ logits,
                      const int* __restrict__ iter_p, float* __restrict__ wsf,
                      unsigned short* __restrict__ Xc) {
  __shared__ float rowbuf[4][512];
  __shared__ float ssq[4];
  __shared__ int lcnt[32];
  __shared__ float lcsum[32];
  __shared__ unsigned lpres;
  __shared__ float red_[4];
  __shared__ int lastblk;
  const int tid = threadIdx.x, w = tid >> 6, lane = tid & 63;
  const int b = blockIdx.x;
  if (tid < 32) { lcnt[tid] = 0; lcsum[tid] = 0.f; }
  if (tid == 0) lpres = 0u;

  float c0acc = 0.f, c1acc = 0.f, ssqacc = 0.f;
  for (int g = 0; g < 4; ++g) {           // 4 row-groups of 4 rows = 16 rows/block
    const int row = (b * 4 + g) * 4 + w;
    const float* p = (row < B) ? src + (size_t)row * D : tgt + (size_t)(row - B) * D;
    float4 a = ((const float4*)p)[lane], bb = ((const float4*)p)[lane + 64];
    ushort4 ha, la, hb, lb;
    ha.x = f2bf(a.x); la.x = f2bf(a.x - bf2f(ha.x));
    ha.y = f2bf(a.y); la.y = f2bf(a.y - bf2f(ha.y));
    ha.z = f2bf(a.z); la.z = f2bf(a.z - bf2f(ha.z));
    ha.w = f2bf(a.w); la.w = f2bf(a.w - bf2f(ha.w));
    hb.x = f2bf(bb.x); lb.x = f2bf(bb.x - bf2f(hb.x));
    hb.y = f2bf(bb.y); lb.y = f2bf(bb.y - bf2f(hb.y));
    hb.z = f2bf(bb.z); lb.z = f2bf(bb.z - bf2f(hb.z));
    hb.w = f2bf(bb.w); lb.w = f2bf(bb.w - bf2f(hb.w));
    size_t rb8 = (size_t)row * 1024;
    *(ushort4*)(Xc + rb8 + lane * 4)       = ha;   // hi cols 0..255
    *(ushort4*)(Xc + rb8 + 256 + lane * 4) = hb;   // hi cols 256..511
    *(ushort4*)(Xc + rb8 + 512 + lane * 4) = la;   // lo cols 0..255
    *(ushort4*)(Xc + rb8 + 768 + lane * 4) = lb;   // lo cols 256..511
    float s = a.x*a.x + a.y*a.y + a.z*a.z + a.w*a.w
            + bb.x*bb.x + bb.y*bb.y + bb.z*bb.z + bb.w*bb.w;
    *(float4*)&rowbuf[w][lane * 4] = a;
    *(float4*)&rowbuf[w][256 + lane * 4] = bb;
    #pragma unroll
    for (int off = 32; off; off >>= 1) s += __shfl_down(s, off);
    if (lane == 0) { wsf[WS_SQ + row] = s; ssq[w] = s; }
    __syncthreads();
    c0acc += rowbuf[0][tid] + rowbuf[1][tid] + rowbuf[2][tid] + rowbuf[3][tid];
    c1acc += rowbuf[0][tid+256] + rowbuf[1][tid+256] + rowbuf[2][tid+256] + rowbuf[3][tid+256];
    if (tid == 0) ssqacc += ssq[0] + ssq[1] + ssq[2] + ssq[3];
    __syncthreads();
  }
  // class stats for this block's 16 rows
  {
    const int r0 = b * 16;
    if (r0 < B) {
      if (tid < 16) atomicAdd(&lcnt[label[r0 + tid]], 1);
      __syncthreads();
      if (tid < NCLS && lcnt[tid]) atomicAdd((int*)&wsf[WS_HIST] + tid, lcnt[tid]);
    } else {
      if (tid < 16) {
        const float* lp = logits + (size_t)(r0 - B + tid) * NCLS;
        float mx = -1e30f; int am = 0;
        #pragma unroll
        for (int c = 0; c < NCLS; c++) {
          float v = lp[c];
          atomicAdd(&lcsum[c], v);
          if (v > mx) { mx = v; am = c; }  // strict >: first max, matches argmax
        }
        atomicOr(&lpres, 1u << am);
      }
      __syncthreads();
      if (tid < NCLS) atomicAdd(&wsf[WS_CSUM + tid], lcsum[tid]);
      if (tid == 0) atomicOr((unsigned*)&wsf[WS_PRES], lpres);
    }
  }
  // one bucketed atomic set per block
  const int bkt = (b & 7) * 512;
  atomicAdd(&wsf[WS_COLP + bkt + tid], c0acc);
  atomicAdd(&wsf[WS_COLP + bkt + 256 + tid], c1acc);
  if (tid == 0) atomicAdd(&wsf[WS_SUMSQB + (b & 7)], ssqacc);

  // done-counter; last block finalizes stats
  __syncthreads();
  if (tid == 0)
    lastblk = (__hip_atomic_fetch_add((int*)&wsf[WS_CNT2], 1,
               __ATOMIC_RELEASE, __HIP_MEMORY_SCOPE_AGENT) == NPRE - 1);
  __syncthreads();
  if (!lastblk) return;
  __threadfence();  // acquire: see all blocks' atomics/stores
  float cs0 = 0.f, cs1 = 0.f;
  #pragma unroll
  for (int bk = 0; bk < 8; bk++) {
    cs0 += wsf[WS_COLP + bk * 512 + tid];
    cs1 += wsf[WS_COLP + bk * 512 + 256 + tid];
  }
  float v = cs0 * cs0 + cs1 * cs1;
  #pragma unroll
  for (int off = 32; off; off >>= 1) v += __shfl_down(v, off);
  if (lane == 0) red_[w] = v;
  __syncthreads();
  if (tid == 0) {
    unsigned presT = *(unsigned*)&wsf[WS_PRES];
    int cm = 0;
    for (int c = 0; c < NCLS; c++) {
      int cnt = ((int*)&wsf[WS_HIST])[c];
      bool m = (cnt > 0) && ((presT >> c) & 1u);
      if (m) cm++;
      wsf[WS_SVAL + c] = m ? 1.f / (float)cnt : 0.f;
      float cs = wsf[WS_CSUM + c]; if (cs == 0.f) cs = 100.f;
      wsf[WS_TVAL + c] = m ? -1.f / cs : 0.f;
    }
    wsf[WS_SVAL + 31] = 0.f; wsf[WS_TVAL + 31] = 0.f;
    float scale = (cm > 0) ? 1.f / (float)cm : 0.f;
    float pp = (float)iter_p[0] / 1000.f;
    float lamb = 2.f / (1.f + __expf(-pp)) - 1.f;
    wsf[WS_SL] = scale * lamb;
    double colnorm2 = (double)red_[0] + red_[1] + red_[2] + red_[3];
    double sumsq = 0.0;
    for (int bk = 0; bk < 8; bk++) sumsq += (double)wsf[WS_SUMSQB + bk];
    double sumL2 = 2.0 * (double)N * sumsq - 2.0 * colnorm2;
    wsf[WS_NBT] = (float)(-((double)N * (double)N - (double)N) / (4.0 * sumL2));
  }
}

// loss = sum_{tile} mult * K(d2) .* (Q_i Q_j^T), bf16 MFMA hi/lo (R2 structure)
// launch_bounds(256,3): 84 VGPR + 64 AGPR fits 3 waves/SIMD with NO spill;
// (256,4) forces 64 VGPR -> 99 MB scratch spill traffic, 230 us (R6 post-mortem)
__launch_bounds__(256, 3)
__global__ void k_main(const unsigned short* __restrict__ Xc,
                       const int* __restrict__ label, const float* __restrict__ logits,
                       float* __restrict__ wsf, float* __restrict__ out) {
  __shared__ __align__(16) short tileA[BT * BKB];   // 16 KB, XOR-swizzled
  __shared__ __align__(16) short tileB[BT * BKB];   // 16 KB
  __shared__ float sqi[BT], sqj[BT];
  __shared__ float red[4];

  // triangular block decode: bi <= bj, S(bi) = bi*(129-bi)/2
  int bid = blockIdx.x;
  int bi = (int)(64.5f - sqrtf(64.5f * 64.5f - 2.0f * (float)bid));
  while (bi > 0 && bid < (bi * (129 - bi)) / 2) --bi;
  while (bid >= ((bi + 1) * (128 - bi)) / 2) ++bi;
  int bj = bi + (bid - (bi * (129 - bi)) / 2);
  const int i0 = bi * BT, j0 = bj * BT;
  const float mult = (bi == bj) ? 1.f : 2.f;

  const int tid = threadIdx.x;
  const int w = tid >> 6, lane = tid & 63;
  const int woff_m = (w >> 1) * 64, woff_n = (w & 1) * 64;
  const int fr = lane & 15, fg = lane >> 4;       // fragment row / k-group
  const int srow = lane >> 3;                     // staging row-in-8
  const int sgrp = (lane & 7) ^ srow;             // staging logical granule

  if (tid < 128) sqi[tid] = wsf[WS_SQ + i0 + tid];
  else           sqj[tid - 128] = wsf[WS_SQ + j0 + (tid - 128)];
  const float nbt = wsf[WS_NBT];

  f32x4 acc[4][4];
  #pragma unroll
  for (int mt = 0; mt < 4; mt++)
    #pragma unroll
    for (int nt = 0; nt < 4; nt++) acc[mt][nt] = (f32x4){0.f, 0.f, 0.f, 0.f};

  for (int it = 0; it < NITER; ++it) {
    // segment remap: A' = [hi|lo|hi], B' = [hi|hi|lo] over Xc rows [hi(512)|lo(512)]
    const int offA = (it < 16 ? it : it - 16) * BKB;
    const int offB = (it < 8 ? it : it - 8) * BKB;
    __syncthreads();
    #pragma unroll
    for (int q = 0; q < 4; ++q) {
      const int inst = w * 4 + q;                  // 0..15, 8 rows each
      const int rl = inst * 8 + srow;              // local row 0..127
      async_lds16(Xc + (size_t)(i0 + rl) * 1024 + offA + sgrp * 8,
                  tileA + inst * 512);
      async_lds16(Xc + (size_t)(j0 + rl) * 1024 + offB + sgrp * 8,
                  tileB + inst * 512);
    }
    __syncthreads();
    #pragma unroll
    for (int ks = 0; ks < 2; ++ks) {
      bf16x8 af[4], bfr[4];
      #pragma unroll
      for (int mt = 0; mt < 4; mt++)
        af[mt] = frag_read(tileA, woff_m + mt * 16 + fr, ks * 4 + fg);
      #pragma unroll
      for (int nt = 0; nt < 4; nt++)
        bfr[nt] = frag_read(tileB, woff_n + nt * 16 + fr, ks * 4 + fg);
      #pragma unroll
      for (int mt = 0; mt < 4; mt++)
        #pragma unroll
        for (int nt = 0; nt < 4; nt++)
          acc[mt][nt] = __builtin_amdgcn_mfma_f32_16x16x32_bf16(
              af[mt], bfr[nt], acc[mt][nt], 0, 0, 0);
    }
  }

  // acc -> multi-band Gaussian kernel: t + t^2 + t^4 + t^8 + t^16
  float sj4[4], si16[4][4];
  #pragma unroll
  for (int nt = 0; nt < 4; nt++) sj4[nt] = sqj[woff_n + nt * 16 + fr];
  #pragma unroll
  for (int mt = 0; mt < 4; mt++)
    #pragma unroll
    for (int t = 0; t < 4; t++) si16[mt][t] = sqi[woff_m + mt * 16 + fg * 4 + t];
  #pragma unroll
  for (int mt = 0; mt < 4; mt++)
    #pragma unroll
    for (int nt = 0; nt < 4; nt++)
      #pragma unroll
      for (int t = 0; t < 4; t++) {
        float d2 = fmaxf(si16[mt][t] + sj4[nt] - 2.f * acc[mt][nt][t], 0.f);
        float e1 = __expf(d2 * nbt);
        float e2 = e1 * e1, e4 = e2 * e2, e8 = e4 * e4, e16 = e8 * e8;
        acc[mt][nt][t] = ((e16 + e8) + (e4 + e2)) + e1;
      }

  // build Q tiles (hi|lo bf16) into reused LDS, same swizzle
  __syncthreads();
  {
    const int t = tid & 127;
    short* qt = (tid < 128) ? tileA : tileB;
    const int gq = ((tid < 128) ? i0 : j0) + t;
    const int lab = (gq < B) ? label[gq] : -1;
    const float sv = (gq < B) ? wsf[WS_SVAL + lab] : 0.f;
    const float* lp = (gq < B) ? (const float*)0 : logits + (size_t)(gq - B) * NCLS;
    #pragma unroll
    for (int g = 0; g < 8; ++g) {
      u16x8 pack = (u16x8){0,0,0,0,0,0,0,0};
      const int cbase = (g & 3) * 8;
      if (gq < B) {
        if (lab >= cbase && lab < cbase + 8) {
          unsigned short h = f2bf(sv);
          pack[lab - cbase] = (g < 4) ? h : f2bf(sv - bf2f(h));
        }
      } else {
        #pragma unroll
        for (int jc = 0; jc < 8; ++jc) {
          int cc = cbase + jc;
          if (cc < NCLS) {
            float vq = lp[cc] * wsf[WS_TVAL + cc];
            unsigned short h = f2bf(vq);
            pack[jc] = (g < 4) ? h : f2bf(vq - bf2f(h));
          }
        }
      }
      int phys = t * 8 + (g ^ (t & 7));
      *(u16x8*)(qt + phys * 8) = pack;
    }
  }
  __syncthreads();

  // Gram via MFMA (K=96: hi.hi + lo.hi + hi.lo), elementwise-dot with kernel values
  float part = 0.f;
  #pragma unroll
  for (int ch = 0; ch < 3; ++ch) {
    const int ab = (ch == 1) ? 4 : 0, bb = (ch == 2) ? 4 : 0;
    bf16x8 af[4], bfr[4];
    #pragma unroll
    for (int mt = 0; mt < 4; mt++)
      af[mt] = frag_read(tileA, woff_m + mt * 16 + fr, ab + fg);
    #pragma unroll
    for (int nt = 0; nt < 4; nt++)
      bfr[nt] = frag_read(tileB, woff_n + nt * 16 + fr, bb + fg);
    #pragma unroll
    for (int mt = 0; mt < 4; mt++)
      #pragma unroll
      for (int nt = 0; nt < 4; nt++) {
        f32x4 z = (f32x4){0.f, 0.f, 0.f, 0.f};
        f32x4 g = __builtin_amdgcn_mfma_f32_16x16x32_bf16(af[mt], bfr[nt], z, 0, 0, 0);
        part += acc[mt][nt].x * g.x + acc[mt][nt].y * g.y
              + acc[mt][nt].z * g.z + acc[mt][nt].w * g.w;
      }
  }
  part *= mult;
  #pragma unroll
  for (int off = 32; off; off >>= 1) part += __shfl_down(part, off);
  if (lane == 0) red[w] = part;
  __syncthreads();

  // wave-0 finalize: bucketed atomic + release counter; last block sums & writes out
  if (w == 0) {
    float bs = red[0] + red[1] + red[2] + red[3];
    if (lane == 0) atomicAdd(&wsf[WS_ACCB + (blockIdx.x & 63) * 16], bs);
    int old = 0;
    if (lane == 0)
      old = __hip_atomic_fetch_add((int*)&wsf[WS_CNT], 1,
                                   __ATOMIC_RELEASE, __HIP_MEMORY_SCOPE_AGENT);
    old = __shfl(old, 0);
    if (old == NBLK - 1) {
      __builtin_amdgcn_fence(__ATOMIC_ACQUIRE, "agent");
      float t = __hip_atomic_load(&wsf[WS_ACCB + lane * 16],
                                  __ATOMIC_RELAXED, __HIP_MEMORY_SCOPE_AGENT);
      #pragma unroll
      for (int off = 32; off; off >>= 1) t += __shfl_down(t, off);
      if (lane == 0) out[0] = t * wsf[WS_SL];
    }
  }
}

extern "C" void kernel_launch(void* const* d_in, const int* in_sizes, int n_in,
                              void* d_out, int out_size, void* d_ws, size_t ws_size,
                              hipStream_t stream) {
  const float* src    = (const float*)d_in[0];
  const float* tgt    = (const float*)d_in[1];
  const int*   label  = (const int*)d_in[2];
  const float* logits = (const float*)d_in[3];
  const int*   iter_p = (const int*)d_in[4];
  float* wsf = (float*)d_ws;
  unsigned short* Xc = (unsigned short*)((char*)d_ws + WS_XC_BYTES);
  float* out = (float*)d_out;

  hipMemsetAsync(d_ws, 0, 24576, stream);   // zero scalars/counters/buckets/stats
  k_pre<<<NPRE, 256, 0, stream>>>(src, tgt, label, logits, iter_p, wsf, Xc);
  k_main<<<NBLK, 256, 0, stream>>>(Xc, label, logits, wsf, out);
}

// Round 8
// 276.829 us; speedup vs baseline: 2.3181x; 1.0588x over previous
//
#include <hip/hip_runtime.h>
#include <math.h>

#define NCLS 31
#define B 4096
#define D 512
#define N 8192
#define BT 128
#define NT (N / BT)               // 64 tiles per dim
#define NBLK (NT * (NT + 1) / 2)  // 2080 upper-tri tiles
#define BK32 32                   // bf16 K-chunk per iteration (double-buffered)
#define NITER 48                  // K=1536 effective (hi|lo|hi vs hi|hi|lo)
#define NPRE 512                  // k_pre blocks (16 rows each)

// ws float-index layout (memset zeroes first 24576 B = 6144 floats)
#define WS_SUMSQB 0      // 8 bucketed sumsq accumulators
#define WS_NBT    9
#define WS_SL     10
#define WS_CNT    11     // int done-counter (k_main)
#define WS_CNT2   12     // int done-counter (k_pre)
#define WS_HIST   16     // 31 ints
#define WS_PRES   47     // unsigned mask
#define WS_CSUM   48     // 31 floats
#define WS_SVAL   80     // 32
#define WS_TVAL   112    // 32
#define WS_ACCB   256    // 64 buckets, stride 16 floats (one line each)
#define WS_COLP   1280   // 8*512 bucketed column-sum partials (ends 5376)
#define WS_SQ     5376   // 8192 row squared norms (fully written by k_pre)
#define WS_XC_BYTES 65536  // Xc: bf16 [8192][1024] (hi|lo), 16 MB

typedef __attribute__((ext_vector_type(8))) short bf16x8;
typedef __attribute__((ext_vector_type(4))) float f32x4;
typedef __attribute__((ext_vector_type(8))) unsigned short u16x8;

__device__ __forceinline__ unsigned short f2bf(float x) {
  unsigned u = __float_as_uint(x);
  u += 0x7fffu + ((u >> 16) & 1u);  // RNE (inputs finite)
  return (unsigned short)(u >> 16);
}
__device__ __forceinline__ float bf2f(unsigned short b) {
  return __uint_as_float(((unsigned)b) << 16);
}

__device__ __forceinline__ void async_lds16(const unsigned short* g, const short* l) {
  __builtin_amdgcn_global_load_lds(
      (const __attribute__((address_space(1))) unsigned int*)g,
      (__attribute__((address_space(3))) unsigned int*)l, 16, 0, 0);
}

// BK=32 tile: rows of 64 B = 4 granules of 16 B; XOR swizzle on (r>>1)&3
// (frag ds_read_b128: 16 lanes, even/odd rows split bank halves, 4 granule
//  phases rotate within each half -> max 2-way = free per m136)
__device__ __forceinline__ bf16x8 frag32(const short* buf, int r, int g) {
  int sg = g ^ ((r >> 1) & 3);
  return *(const bf16x8*)(buf + (r * 4 + sg) * 8);
}

// k_pre: convert + row sumsq + colsum (register-accumulated, one bucketed atomic
// set per block) + class stats; LAST block (done-counter) finalizes all stats.
__global__ void k_pre(const float* __restrict__ src, const float* __restrict__ tgt,
                      const int* __restrict__ label, const float* __restrict__ logits,
                      const int* __restrict__ iter_p, float* __restrict__ wsf,
                      unsigned short* __restrict__ Xc) {
  __shared__ float rowbuf[4][512];
  __shared__ float ssq[4];
  __shared__ int lcnt[32];
  __shared__ float lcsum[32];
  __shared__ unsigned lpres;
  __shared__ float red_[4];
  __shared__ int lastblk;
  const int tid = threadIdx.x, w = tid >> 6, lane = tid & 63;
  const int b = blockIdx.x;
  if (tid < 32) { lcnt[tid] = 0; lcsum[tid] = 0.f; }
  if (tid == 0) lpres = 0u;

  float c0acc = 0.f, c1acc = 0.f, ssqacc = 0.f;
  for (int g = 0; g < 4; ++g) {           // 4 row-groups of 4 rows = 16 rows/block
    const int row = (b * 4 + g) * 4 + w;
    const float* p = (row < B) ? src + (size_t)row * D : tgt + (size_t)(row - B) * D;
    float4 a = ((const float4*)p)[lane], bb = ((const float4*)p)[lane + 64];
    ushort4 ha, la, hb, lb;
    ha.x = f2bf(a.x); la.x = f2bf(a.x - bf2f(ha.x));
    ha.y = f2bf(a.y); la.y = f2bf(a.y - bf2f(ha.y));
    ha.z = f2bf(a.z); la.z = f2bf(a.z - bf2f(ha.z));
    ha.w = f2bf(a.w); la.w = f2bf(a.w - bf2f(ha.w));
    hb.x = f2bf(bb.x); lb.x = f2bf(bb.x - bf2f(hb.x));
    hb.y = f2bf(bb.y); lb.y = f2bf(bb.y - bf2f(hb.y));
    hb.z = f2bf(bb.z); lb.z = f2bf(bb.z - bf2f(hb.z));
    hb.w = f2bf(bb.w); lb.w = f2bf(bb.w - bf2f(hb.w));
    size_t rb8 = (size_t)row * 1024;
    *(ushort4*)(Xc + rb8 + lane * 4)       = ha;   // hi cols 0..255
    *(ushort4*)(Xc + rb8 + 256 + lane * 4) = hb;   // hi cols 256..511
    *(ushort4*)(Xc + rb8 + 512 + lane * 4) = la;   // lo cols 0..255
    *(ushort4*)(Xc + rb8 + 768 + lane * 4) = lb;   // lo cols 256..511
    float s = a.x*a.x + a.y*a.y + a.z*a.z + a.w*a.w
            + bb.x*bb.x + bb.y*bb.y + bb.z*bb.z + bb.w*bb.w;
    *(float4*)&rowbuf[w][lane * 4] = a;
    *(float4*)&rowbuf[w][256 + lane * 4] = bb;
    #pragma unroll
    for (int off = 32; off; off >>= 1) s += __shfl_down(s, off);
    if (lane == 0) { wsf[WS_SQ + row] = s; ssq[w] = s; }
    __syncthreads();
    c0acc += rowbuf[0][tid] + rowbuf[1][tid] + rowbuf[2][tid] + rowbuf[3][tid];
    c1acc += rowbuf[0][tid+256] + rowbuf[1][tid+256] + rowbuf[2][tid+256] + rowbuf[3][tid+256];
    if (tid == 0) ssqacc += ssq[0] + ssq[1] + ssq[2] + ssq[3];
    __syncthreads();
  }
  // class stats for this block's 16 rows
  {
    const int r0 = b * 16;
    if (r0 < B) {
      if (tid < 16) atomicAdd(&lcnt[label[r0 + tid]], 1);
      __syncthreads();
      if (tid < NCLS && lcnt[tid]) atomicAdd((int*)&wsf[WS_HIST] + tid, lcnt[tid]);
    } else {
      if (tid < 16) {
        const float* lp = logits + (size_t)(r0 - B + tid) * NCLS;
        float mx = -1e30f; int am = 0;
        #pragma unroll
        for (int c = 0; c < NCLS; c++) {
          float v = lp[c];
          atomicAdd(&lcsum[c], v);
          if (v > mx) { mx = v; am = c; }  // strict >: first max, matches argmax
        }
        atomicOr(&lpres, 1u << am);
      }
      __syncthreads();
      if (tid < NCLS) atomicAdd(&wsf[WS_CSUM + tid], lcsum[tid]);
      if (tid == 0) atomicOr((unsigned*)&wsf[WS_PRES], lpres);
    }
  }
  // one bucketed atomic set per block
  const int bkt = (b & 7) * 512;
  atomicAdd(&wsf[WS_COLP + bkt + tid], c0acc);
  atomicAdd(&wsf[WS_COLP + bkt + 256 + tid], c1acc);
  if (tid == 0) atomicAdd(&wsf[WS_SUMSQB + (b & 7)], ssqacc);

  // done-counter; last block finalizes stats
  __syncthreads();
  if (tid == 0)
    lastblk = (__hip_atomic_fetch_add((int*)&wsf[WS_CNT2], 1,
               __ATOMIC_RELEASE, __HIP_MEMORY_SCOPE_AGENT) == NPRE - 1);
  __syncthreads();
  if (!lastblk) return;
  __threadfence();  // acquire: see all blocks' atomics/stores
  float cs0 = 0.f, cs1 = 0.f;
  #pragma unroll
  for (int bk = 0; bk < 8; bk++) {
    cs0 += wsf[WS_COLP + bk * 512 + tid];
    cs1 += wsf[WS_COLP + bk * 512 + 256 + tid];
  }
  float v = cs0 * cs0 + cs1 * cs1;
  #pragma unroll
  for (int off = 32; off; off >>= 1) v += __shfl_down(v, off);
  if (lane == 0) red_[w] = v;
  __syncthreads();
  if (tid == 0) {
    unsigned presT = *(unsigned*)&wsf[WS_PRES];
    int cm = 0;
    for (int c = 0; c < NCLS; c++) {
      int cnt = ((int*)&wsf[WS_HIST])[c];
      bool m = (cnt > 0) && ((presT >> c) & 1u);
      if (m) cm++;
      wsf[WS_SVAL + c] = m ? 1.f / (float)cnt : 0.f;
      float cs = wsf[WS_CSUM + c]; if (cs == 0.f) cs = 100.f;
      wsf[WS_TVAL + c] = m ? -1.f / cs : 0.f;
    }
    wsf[WS_SVAL + 31] = 0.f; wsf[WS_TVAL + 31] = 0.f;
    float scale = (cm > 0) ? 1.f / (float)cm : 0.f;
    float pp = (float)iter_p[0] / 1000.f;
    float lamb = 2.f / (1.f + __expf(-pp)) - 1.f;
    wsf[WS_SL] = scale * lamb;
    double colnorm2 = (double)red_[0] + red_[1] + red_[2] + red_[3];
    double sumsq = 0.0;
    for (int bk = 0; bk < 8; bk++) sumsq += (double)wsf[WS_SUMSQB + bk];
    double sumL2 = 2.0 * (double)N * sumsq - 2.0 * colnorm2;
    wsf[WS_NBT] = (float)(-((double)N * (double)N - (double)N) / (4.0 * sumL2));
  }
}

// loss = sum_{tile} mult * K(d2) .* (Q_i Q_j^T), bf16 MFMA hi/lo.
// Async double-buffered K-loop (BK=32): global_load_lds for iter i+1 issued
// right after the barrier, compute on iter i hides the load latency; zero
// VGPR cost (unlike R3's register prefetch), LDS stays 34 KB -> 3 blocks/CU.
// launch_bounds(256,3): (256,4) forces 64 VGPR -> spills (R6 post-mortem).
__launch_bounds__(256, 3)
__global__ void k_main(const unsigned short* __restrict__ Xc,
                       const int* __restrict__ label, const float* __restrict__ logits,
                       float* __restrict__ wsf, float* __restrict__ out) {
  __shared__ __align__(16) short tA[2][BT * BK32];   // 2 x 8 KB
  __shared__ __align__(16) short tB[2][BT * BK32];   // 2 x 8 KB
  __shared__ float sqi[BT], sqj[BT];
  __shared__ float red[4];

  // triangular block decode: bi <= bj, S(bi) = bi*(129-bi)/2
  int bid = blockIdx.x;
  int bi = (int)(64.5f - sqrtf(64.5f * 64.5f - 2.0f * (float)bid));
  while (bi > 0 && bid < (bi * (129 - bi)) / 2) --bi;
  while (bid >= ((bi + 1) * (128 - bi)) / 2) ++bi;
  int bj = bi + (bid - (bi * (129 - bi)) / 2);
  const int i0 = bi * BT, j0 = bj * BT;
  const float mult = (bi == bj) ? 1.f : 2.f;

  const int tid = threadIdx.x;
  const int w = tid >> 6, lane = tid & 63;
  const int woff_m = (w >> 1) * 64, woff_n = (w & 1) * 64;
  const int fr = lane & 15, fg = lane >> 4;       // fragment row / k-group
  // staging: each inst covers 16 rows x 64 B; lane -> (r_local, swizzled granule)
  const int s_r  = lane >> 2;                     // r_local 0..15
  const int s_g  = (lane & 3) ^ ((s_r >> 1) & 3); // logical granule (inverts swizzle)

  if (tid < 128) sqi[tid] = wsf[WS_SQ + i0 + tid];
  else           sqj[tid - 128] = wsf[WS_SQ + j0 + (tid - 128)];
  const float nbt = wsf[WS_NBT];

  f32x4 acc[4][4];
  #pragma unroll
  for (int mt = 0; mt < 4; mt++)
    #pragma unroll
    for (int nt = 0; nt < 4; nt++) acc[mt][nt] = (f32x4){0.f, 0.f, 0.f, 0.f};

  // segment remap: A' = [hi|lo|hi], B' = [hi|hi|lo] over Xc row [hi(512)|lo(512)]
  // issue staging for iteration `it` into buffer `bf`
  #define ISSUE(it, bf) do {                                                   \
    const int offA = ((it) < 16) ? (it) * 32                                   \
                     : ((it) < 32 ? 512 + ((it) - 16) * 32 : ((it) - 32) * 32);\
    const int offB = ((it) < 16) ? (it) * 32                                   \
                     : ((it) < 32 ? ((it) - 16) * 32 : 512 + ((it) - 32) * 32);\
    _Pragma("unroll")                                                          \
    for (int q = 0; q < 2; ++q) {                                              \
      const int inst = w * 2 + q;              /* 0..7, 16 rows each */        \
      const int rl = inst * 16 + s_r;                                          \
      async_lds16(Xc + (size_t)(i0 + rl) * 1024 + offA + s_g * 8,              \
                  &tA[bf][inst * 512]);                                        \
      async_lds16(Xc + (size_t)(j0 + rl) * 1024 + offB + s_g * 8,              \
                  &tB[bf][inst * 512]);                                        \
    }                                                                          \
  } while (0)

  ISSUE(0, 0);
  int cur = 0;
  for (int it = 0; it < NITER; ++it) {
    __syncthreads();   // drains cur's loads (issued ~1 iter ago); prev reads done
    if (it + 1 < NITER) ISSUE(it + 1, cur ^ 1);
    bf16x8 af[4], bfr[4];
    #pragma unroll
    for (int mt = 0; mt < 4; mt++)
      af[mt] = frag32(tA[cur], woff_m + mt * 16 + fr, fg);
    #pragma unroll
    for (int nt = 0; nt < 4; nt++)
      bfr[nt] = frag32(tB[cur], woff_n + nt * 16 + fr, fg);
    #pragma unroll
    for (int mt = 0; mt < 4; mt++)
      #pragma unroll
      for (int nt = 0; nt < 4; nt++)
        acc[mt][nt] = __builtin_amdgcn_mfma_f32_16x16x32_bf16(
            af[mt], bfr[nt], acc[mt][nt], 0, 0, 0);
    cur ^= 1;
  }

  // acc -> multi-band Gaussian kernel: t + t^2 + t^4 + t^8 + t^16
  float sj4[4], si16[4][4];
  #pragma unroll
  for (int nt = 0; nt < 4; nt++) sj4[nt] = sqj[woff_n + nt * 16 + fr];
  #pragma unroll
  for (int mt = 0; mt < 4; mt++)
    #pragma unroll
    for (int t = 0; t < 4; t++) si16[mt][t] = sqi[woff_m + mt * 16 + fg * 4 + t];
  #pragma unroll
  for (int mt = 0; mt < 4; mt++)
    #pragma unroll
    for (int nt = 0; nt < 4; nt++)
      #pragma unroll
      for (int t = 0; t < 4; t++) {
        float d2 = fmaxf(si16[mt][t] + sj4[nt] - 2.f * acc[mt][nt][t], 0.f);
        float e1 = __expf(d2 * nbt);
        float e2 = e1 * e1, e4 = e2 * e2, e8 = e4 * e4, e16 = e8 * e8;
        acc[mt][nt][t] = ((e16 + e8) + (e4 + e2)) + e1;
      }

  // build Q tiles: Qi-hi->tA[0], Qi-lo->tA[1], Qj-hi->tB[0], Qj-lo->tB[1]
  __syncthreads();
  {
    const int t = tid & 127;
    short* qh = (tid < 128) ? tA[0] : tB[0];
    short* ql = (tid < 128) ? tA[1] : tB[1];
    const int gq = ((tid < 128) ? i0 : j0) + t;
    const int lab = (gq < B) ? label[gq] : -1;
    const float sv = (gq < B) ? wsf[WS_SVAL + lab] : 0.f;
    const float* lp = (gq < B) ? (const float*)0 : logits + (size_t)(gq - B) * NCLS;
    #pragma unroll
    for (int g = 0; g < 4; ++g) {
      u16x8 ph = (u16x8){0,0,0,0,0,0,0,0}, pl = (u16x8){0,0,0,0,0,0,0,0};
      const int cbase = g * 8;
      if (gq < B) {
        if (lab >= cbase && lab < cbase + 8) {
          unsigned short h = f2bf(sv);
          ph[lab - cbase] = h;
          pl[lab - cbase] = f2bf(sv - bf2f(h));
        }
      } else {
        #pragma unroll
        for (int jc = 0; jc < 8; ++jc) {
          int cc = cbase + jc;
          if (cc < NCLS) {
            float vq = lp[cc] * wsf[WS_TVAL + cc];
            unsigned short h = f2bf(vq);
            ph[jc] = h;
            pl[jc] = f2bf(vq - bf2f(h));
          }
        }
      }
      int phys = (t * 4 + (g ^ ((t >> 1) & 3))) * 8;
      *(u16x8*)(qh + phys) = ph;
      *(u16x8*)(ql + phys) = pl;
    }
  }
  __syncthreads();

  // Gram via MFMA (K=96: hi.hi + lo.hi + hi.lo), elementwise-dot with kernel values
  float part = 0.f;
  #pragma unroll
  for (int ch = 0; ch < 3; ++ch) {
    const short* qa = (ch == 1) ? tA[1] : tA[0];
    const short* qb = (ch == 2) ? tB[1] : tB[0];
    bf16x8 af[4], bfr[4];
    #pragma unroll
    for (int mt = 0; mt < 4; mt++)
      af[mt] = frag32(qa, woff_m + mt * 16 + fr, fg);
    #pragma unroll
    for (int nt = 0; nt < 4; nt++)
      bfr[nt] = frag32(qb, woff_n + nt * 16 + fr, fg);
    #pragma unroll
    for (int mt = 0; mt < 4; mt++)
      #pragma unroll
      for (int nt = 0; nt < 4; nt++) {
        f32x4 z = (f32x4){0.f, 0.f, 0.f, 0.f};
        f32x4 g = __builtin_amdgcn_mfma_f32_16x16x32_bf16(af[mt], bfr[nt], z, 0, 0, 0);
        part += acc[mt][nt].x * g.x + acc[mt][nt].y * g.y
              + acc[mt][nt].z * g.z + acc[mt][nt].w * g.w;
      }
  }
  part *= mult;
  #pragma unroll
  for (int off = 32; off; off >>= 1) part += __shfl_down(part, off);
  if (lane == 0) red[w] = part;
  __syncthreads();

  // wave-0 finalize: bucketed atomic + release counter; last block sums & writes out
  if (w == 0) {
    float bs = red[0] + red[1] + red[2] + red[3];
    if (lane == 0) atomicAdd(&wsf[WS_ACCB + (blockIdx.x & 63) * 16], bs);
    int old = 0;
    if (lane == 0)
      old = __hip_atomic_fetch_add((int*)&wsf[WS_CNT], 1,
                                   __ATOMIC_RELEASE, __HIP_MEMORY_SCOPE_AGENT);
    old = __shfl(old, 0);
    if (old == NBLK - 1) {
      __builtin_amdgcn_fence(__ATOMIC_ACQUIRE, "agent");
      float t = __hip_atomic_load(&wsf[WS_ACCB + lane * 16],
                                  __ATOMIC_RELAXED, __HIP_MEMORY_SCOPE_AGENT);
      #pragma unroll
      for (int off = 32; off; off >>= 1) t += __shfl_down(t, off);
      if (lane == 0) out[0] = t * wsf[WS_SL];
    }
  }
}

extern "C" void kernel_launch(void* const* d_in, const int* in_sizes, int n_in,
                              void* d_out, int out_size, void* d_ws, size_t ws_size,
                              hipStream_t stream) {
  const float* src    = (const float*)d_in[0];
  const float* tgt    = (const float*)d_in[1];
  const int*   label  = (const int*)d_in[2];
  const float* logits = (const float*)d_in[3];
  const int*   iter_p = (const int*)d_in[4];
  float* wsf = (float*)d_ws;
  unsigned short* Xc = (unsigned short*)((char*)d_ws + WS_XC_BYTES);
  float* out = (float*)d_out;

  hipMemsetAsync(d_ws, 0, 24576, stream);   // zero scalars/counters/buckets/stats
  k_pre<<<NPRE, 256, 0, stream>>>(src, tgt, label, logits, iter_p, wsf, Xc);
  k_main<<<NBLK, 256, 0, stream>>>(Xc, label, logits, wsf, out);
}

// Round 9
// 198.970 us; speedup vs baseline: 3.2251x; 1.3913x over previous
//
#include <hip/hip_runtime.h>
#include <math.h>

#define NCLS 31
#define B 4096
#define D 512
#define N 8192
#define BT 128
#define NT (N / BT)               // 64 tiles per dim
#define NBLK (NT * (NT + 1) / 2)  // 2080 upper-tri tiles
#define BK32 32                   // bf16 K-chunk per iteration (double-buffered)
#define NITER 16                  // K=512: pure-bf16 X dot (error ~5e-7 << 1.2e-4 thr)
#define NPRE 512                  // k_pre blocks (16 rows each)

// ws float-index layout (memset zeroes first 24576 B = 6144 floats)
#define WS_SUMSQB 0      // 8 bucketed sumsq accumulators
#define WS_NBT    9
#define WS_SL     10
#define WS_CNT    11     // int done-counter (k_main)
#define WS_CNT2   12     // int done-counter (k_pre)
#define WS_HIST   16     // 31 ints
#define WS_PRES   47     // unsigned mask
#define WS_CSUM   48     // 31 floats
#define WS_SVAL   80     // 32
#define WS_TVAL   112    // 32
#define WS_ACCB   256    // 64 buckets, stride 16 floats (one line each)
#define WS_COLP   1280   // 8*512 bucketed column-sum partials (ends 5376)
#define WS_SQ     5376   // 8192 row squared norms (fully written by k_pre)
#define WS_XC_BYTES 65536  // Xc: bf16 [8192][512], 8 MB

typedef __attribute__((ext_vector_type(8))) short bf16x8;
typedef __attribute__((ext_vector_type(4))) float f32x4;
typedef __attribute__((ext_vector_type(8))) unsigned short u16x8;

__device__ __forceinline__ unsigned short f2bf(float x) {
  unsigned u = __float_as_uint(x);
  u += 0x7fffu + ((u >> 16) & 1u);  // RNE (inputs finite)
  return (unsigned short)(u >> 16);
}
__device__ __forceinline__ float bf2f(unsigned short b) {
  return __uint_as_float(((unsigned)b) << 16);
}

__device__ __forceinline__ void async_lds16(const unsigned short* g, const short* l) {
  __builtin_amdgcn_global_load_lds(
      (const __attribute__((address_space(1))) unsigned int*)g,
      (__attribute__((address_space(3))) unsigned int*)l, 16, 0, 0);
}

// BK=32 tile: rows of 64 B = 4 granules of 16 B; XOR swizzle on (r>>1)&3
__device__ __forceinline__ bf16x8 frag32(const short* buf, int r, int g) {
  int sg = g ^ ((r >> 1) & 3);
  return *(const bf16x8*)(buf + (r * 4 + sg) * 8);
}

// k_pre: bf16 convert + row sumsq + colsum (register-accumulated, one bucketed
// atomic set per block) + class stats; LAST block finalizes all stats.
__global__ void k_pre(const float* __restrict__ src, const float* __restrict__ tgt,
                      const int* __restrict__ label, const float* __restrict__ logits,
                      const int* __restrict__ iter_p, float* __restrict__ wsf,
                      unsigned short* __restrict__ Xc) {
  __shared__ float rowbuf[4][512];
  __shared__ float ssq[4];
  __shared__ int lcnt[32];
  __shared__ float lcsum[32];
  __shared__ unsigned lpres;
  __shared__ float red_[4];
  __shared__ int lastblk;
  const int tid = threadIdx.x, w = tid >> 6, lane = tid & 63;
  const int b = blockIdx.x;
  if (tid < 32) { lcnt[tid] = 0; lcsum[tid] = 0.f; }
  if (tid == 0) lpres = 0u;

  float c0acc = 0.f, c1acc = 0.f, ssqacc = 0.f;
  for (int g = 0; g < 4; ++g) {           // 4 row-groups of 4 rows = 16 rows/block
    const int row = (b * 4 + g) * 4 + w;
    const float* p = (row < B) ? src + (size_t)row * D : tgt + (size_t)(row - B) * D;
    float4 a = ((const float4*)p)[lane], bb = ((const float4*)p)[lane + 64];
    ushort4 ha, hb;
    ha.x = f2bf(a.x); ha.y = f2bf(a.y); ha.z = f2bf(a.z); ha.w = f2bf(a.w);
    hb.x = f2bf(bb.x); hb.y = f2bf(bb.y); hb.z = f2bf(bb.z); hb.w = f2bf(bb.w);
    size_t rb8 = (size_t)row * 512;
    *(ushort4*)(Xc + rb8 + lane * 4)       = ha;   // cols 0..255
    *(ushort4*)(Xc + rb8 + 256 + lane * 4) = hb;   // cols 256..511
    float s = a.x*a.x + a.y*a.y + a.z*a.z + a.w*a.w
            + bb.x*bb.x + bb.y*bb.y + bb.z*bb.z + bb.w*bb.w;
    *(float4*)&rowbuf[w][lane * 4] = a;
    *(float4*)&rowbuf[w][256 + lane * 4] = bb;
    #pragma unroll
    for (int off = 32; off; off >>= 1) s += __shfl_down(s, off);
    if (lane == 0) { wsf[WS_SQ + row] = s; ssq[w] = s; }
    __syncthreads();
    c0acc += rowbuf[0][tid] + rowbuf[1][tid] + rowbuf[2][tid] + rowbuf[3][tid];
    c1acc += rowbuf[0][tid+256] + rowbuf[1][tid+256] + rowbuf[2][tid+256] + rowbuf[3][tid+256];
    if (tid == 0) ssqacc += ssq[0] + ssq[1] + ssq[2] + ssq[3];
    __syncthreads();
  }
  // class stats for this block's 16 rows
  {
    const int r0 = b * 16;
    if (r0 < B) {
      if (tid < 16) atomicAdd(&lcnt[label[r0 + tid]], 1);
      __syncthreads();
      if (tid < NCLS && lcnt[tid]) atomicAdd((int*)&wsf[WS_HIST] + tid, lcnt[tid]);
    } else {
      if (tid < 16) {
        const float* lp = logits + (size_t)(r0 - B + tid) * NCLS;
        float mx = -1e30f; int am = 0;
        #pragma unroll
        for (int c = 0; c < NCLS; c++) {
          float v = lp[c];
          atomicAdd(&lcsum[c], v);
          if (v > mx) { mx = v; am = c; }  // strict >: first max, matches argmax
        }
        atomicOr(&lpres, 1u << am);
      }
      __syncthreads();
      if (tid < NCLS) atomicAdd(&wsf[WS_CSUM + tid], lcsum[tid]);
      if (tid == 0) atomicOr((unsigned*)&wsf[WS_PRES], lpres);
    }
  }
  // one bucketed atomic set per block
  const int bkt = (b & 7) * 512;
  atomicAdd(&wsf[WS_COLP + bkt + tid], c0acc);
  atomicAdd(&wsf[WS_COLP + bkt + 256 + tid], c1acc);
  if (tid == 0) atomicAdd(&wsf[WS_SUMSQB + (b & 7)], ssqacc);

  // done-counter; last block finalizes stats
  __syncthreads();
  if (tid == 0)
    lastblk = (__hip_atomic_fetch_add((int*)&wsf[WS_CNT2], 1,
               __ATOMIC_RELEASE, __HIP_MEMORY_SCOPE_AGENT) == NPRE - 1);
  __syncthreads();
  if (!lastblk) return;
  __threadfence();  // acquire: see all blocks' atomics/stores
  float cs0 = 0.f, cs1 = 0.f;
  #pragma unroll
  for (int bk = 0; bk < 8; bk++) {
    cs0 += wsf[WS_COLP + bk * 512 + tid];
    cs1 += wsf[WS_COLP + bk * 512 + 256 + tid];
  }
  float v = cs0 * cs0 + cs1 * cs1;
  #pragma unroll
  for (int off = 32; off; off >>= 1) v += __shfl_down(v, off);
  if (lane == 0) red_[w] = v;
  __syncthreads();
  if (tid == 0) {
    unsigned presT = *(unsigned*)&wsf[WS_PRES];
    int cm = 0;
    for (int c = 0; c < NCLS; c++) {
      int cnt = ((int*)&wsf[WS_HIST])[c];
      bool m = (cnt > 0) && ((presT >> c) & 1u);
      if (m) cm++;
      wsf[WS_SVAL + c] = m ? 1.f / (float)cnt : 0.f;
      float cs = wsf[WS_CSUM + c]; if (cs == 0.f) cs = 100.f;
      wsf[WS_TVAL + c] = m ? -1.f / cs : 0.f;
    }
    wsf[WS_SVAL + 31] = 0.f; wsf[WS_TVAL + 31] = 0.f;
    float scale = (cm > 0) ? 1.f / (float)cm : 0.f;
    float pp = (float)iter_p[0] / 1000.f;
    float lamb = 2.f / (1.f + __expf(-pp)) - 1.f;
    wsf[WS_SL] = scale * lamb;
    double colnorm2 = (double)red_[0] + red_[1] + red_[2] + red_[3];
    double sumsq = 0.0;
    for (int bk = 0; bk < 8; bk++) sumsq += (double)wsf[WS_SUMSQB + bk];
    double sumL2 = 2.0 * (double)N * sumsq - 2.0 * colnorm2;
    wsf[WS_NBT] = (float)(-((double)N * (double)N - (double)N) / (4.0 * sumL2));
  }
}

// loss = sum_{tile} mult * K(d2) .* (Q_i Q_j^T).
// X-dot in pure bf16 (K=512): loss-error rms ~5e-7 (see R9 analysis), 300x
// under threshold. Q-Gram keeps hi/lo bf16 (K=96) — real cancellation there.
// launch_bounds(256,3): (256,4) forces 64 VGPR -> spills (R6 post-mortem).
__launch_bounds__(256, 3)
__global__ void k_main(const unsigned short* __restrict__ Xc,
                       const int* __restrict__ label, const float* __restrict__ logits,
                       float* __restrict__ wsf, float* __restrict__ out) {
  __shared__ __align__(16) short tA[2][BT * BK32];   // 2 x 8 KB
  __shared__ __align__(16) short tB[2][BT * BK32];   // 2 x 8 KB
  __shared__ float sqi[BT], sqj[BT];
  __shared__ float red[4];

  // triangular block decode: bi <= bj, S(bi) = bi*(129-bi)/2
  int bid = blockIdx.x;
  int bi = (int)(64.5f - sqrtf(64.5f * 64.5f - 2.0f * (float)bid));
  while (bi > 0 && bid < (bi * (129 - bi)) / 2) --bi;
  while (bid >= ((bi + 1) * (128 - bi)) / 2) ++bi;
  int bj = bi + (bid - (bi * (129 - bi)) / 2);
  const int i0 = bi * BT, j0 = bj * BT;
  const float mult = (bi == bj) ? 1.f : 2.f;

  const int tid = threadIdx.x;
  const int w = tid >> 6, lane = tid & 63;
  const int woff_m = (w >> 1) * 64, woff_n = (w & 1) * 64;
  const int fr = lane & 15, fg = lane >> 4;       // fragment row / k-group
  // staging: each inst covers 16 rows x 64 B; lane -> (r_local, swizzled granule)
  const int s_r  = lane >> 2;                     // r_local 0..15
  const int s_g  = (lane & 3) ^ ((s_r >> 1) & 3); // logical granule (inverts swizzle)

  if (tid < 128) sqi[tid] = wsf[WS_SQ + i0 + tid];
  else           sqj[tid - 128] = wsf[WS_SQ + j0 + (tid - 128)];
  const float nbt = wsf[WS_NBT];

  f32x4 acc[4][4];
  #pragma unroll
  for (int mt = 0; mt < 4; mt++)
    #pragma unroll
    for (int nt = 0; nt < 4; nt++) acc[mt][nt] = (f32x4){0.f, 0.f, 0.f, 0.f};

  // issue staging for iteration `it` (K-offset it*32) into buffer `bf`
  #define ISSUE(it, bf) do {                                                   \
    const int off = (it) * 32;                                                 \
    _Pragma("unroll")                                                          \
    for (int q = 0; q < 2; ++q) {                                              \
      const int inst = w * 2 + q;              /* 0..7, 16 rows each */        \
      const int rl = inst * 16 + s_r;                                          \
      async_lds16(Xc + (size_t)(i0 + rl) * 512 + off + s_g * 8,                \
                  &tA[bf][inst * 512]);                                        \
      async_lds16(Xc + (size_t)(j0 + rl) * 512 + off + s_g * 8,                \
                  &tB[bf][inst * 512]);                                        \
    }                                                                          \
  } while (0)

  ISSUE(0, 0);
  int cur = 0;
  for (int it = 0; it < NITER; ++it) {
    __syncthreads();   // drains cur's loads (issued ~1 iter ago); prev reads done
    if (it + 1 < NITER) ISSUE(it + 1, cur ^ 1);
    bf16x8 af[4], bfr[4];
    #pragma unroll
    for (int mt = 0; mt < 4; mt++)
      af[mt] = frag32(tA[cur], woff_m + mt * 16 + fr, fg);
    #pragma unroll
    for (int nt = 0; nt < 4; nt++)
      bfr[nt] = frag32(tB[cur], woff_n + nt * 16 + fr, fg);
    #pragma unroll
    for (int mt = 0; mt < 4; mt++)
      #pragma unroll
      for (int nt = 0; nt < 4; nt++)
        acc[mt][nt] = __builtin_amdgcn_mfma_f32_16x16x32_bf16(
            af[mt], bfr[nt], acc[mt][nt], 0, 0, 0);
    cur ^= 1;
  }

  // acc -> multi-band Gaussian kernel: t + t^2 + t^4 + t^8 + t^16
  float sj4[4], si16[4][4];
  #pragma unroll
  for (int nt = 0; nt < 4; nt++) sj4[nt] = sqj[woff_n + nt * 16 + fr];
  #pragma unroll
  for (int mt = 0; mt < 4; mt++)
    #pragma unroll
    for (int t = 0; t < 4; t++) si16[mt][t] = sqi[woff_m + mt * 16 + fg * 4 + t];
  #pragma unroll
  for (int mt = 0; mt < 4; mt++)
    #pragma unroll
    for (int nt = 0; nt < 4; nt++)
      #pragma unroll
      for (int t = 0; t < 4; t++) {
        float d2 = fmaxf(si16[mt][t] + sj4[nt] - 2.f * acc[mt][nt][t], 0.f);
        float e1 = __expf(d2 * nbt);
        float e2 = e1 * e1, e4 = e2 * e2, e8 = e4 * e4, e16 = e8 * e8;
        acc[mt][nt][t] = ((e16 + e8) + (e4 + e2)) + e1;
      }

  // build Q tiles: Qi-hi->tA[0], Qi-lo->tA[1], Qj-hi->tB[0], Qj-lo->tB[1]
  __syncthreads();
  {
    const int t = tid & 127;
    short* qh = (tid < 128) ? tA[0] : tB[0];
    short* ql = (tid < 128) ? tA[1] : tB[1];
    const int gq = ((tid < 128) ? i0 : j0) + t;
    const int lab = (gq < B) ? label[gq] : -1;
    const float sv = (gq < B) ? wsf[WS_SVAL + lab] : 0.f;
    const float* lp = (gq < B) ? (const float*)0 : logits + (size_t)(gq - B) * NCLS;
    #pragma unroll
    for (int g = 0; g < 4; ++g) {
      u16x8 ph = (u16x8){0,0,0,0,0,0,0,0}, pl = (u16x8){0,0,0,0,0,0,0,0};
      const int cbase = g * 8;
      if (gq < B) {
        if (lab >= cbase && lab < cbase + 8) {
          unsigned short h = f2bf(sv);
          ph[lab - cbase] = h;
          pl[lab - cbase] = f2bf(sv - bf2f(h));
        }
      } else {
        #pragma unroll
        for (int jc = 0; jc < 8; ++jc) {
          int cc = cbase + jc;
          if (cc < NCLS) {
            float vq = lp[cc] * wsf[WS_TVAL + cc];
            unsigned short h = f2bf(vq);
            ph[jc] = h;
            pl[jc] = f2bf(vq - bf2f(h));
          }
        }
      }
      int phys = (t * 4 + (g ^ ((t >> 1) & 3))) * 8;
      *(u16x8*)(qh + phys) = ph;
      *(u16x8*)(ql + phys) = pl;
    }
  }
  __syncthreads();

  // Gram via MFMA (K=96: hi.hi + lo.hi + hi.lo), elementwise-dot with kernel values
  float part = 0.f;
  #pragma unroll
  for (int ch = 0; ch < 3; ++ch) {
    const short* qa = (ch == 1) ? tA[1] : tA[0];
    const short* qb = (ch == 2) ? tB[1] : tB[0];
    bf16x8 af[4], bfr[4];
    #pragma unroll
    for (int mt = 0; mt < 4; mt++)
      af[mt] = frag32(qa, woff_m + mt * 16 + fr, fg);
    #pragma unroll
    for (int nt = 0; nt < 4; nt++)
      bfr[nt] = frag32(qb, woff_n + nt * 16 + fr, fg);
    #pragma unroll
    for (int mt = 0; mt < 4; mt++)
      #pragma unroll
      for (int nt = 0; nt < 4; nt++) {
        f32x4 z = (f32x4){0.f, 0.f, 0.f, 0.f};
        f32x4 g = __builtin_amdgcn_mfma_f32_16x16x32_bf16(af[mt], bfr[nt], z, 0, 0, 0);
        part += acc[mt][nt].x * g.x + acc[mt][nt].y * g.y
              + acc[mt][nt].z * g.z + acc[mt][nt].w * g.w;
      }
  }
  part *= mult;
  #pragma unroll
  for (int off = 32; off; off >>= 1) part += __shfl_down(part, off);
  if (lane == 0) red[w] = part;
  __syncthreads();

  // wave-0 finalize: bucketed atomic + release counter; last block sums & writes out
  if (w == 0) {
    float bs = red[0] + red[1] + red[2] + red[3];
    if (lane == 0) atomicAdd(&wsf[WS_ACCB + (blockIdx.x & 63) * 16], bs);
    int old = 0;
    if (lane == 0)
      old = __hip_atomic_fetch_add((int*)&wsf[WS_CNT], 1,
                                   __ATOMIC_RELEASE, __HIP_MEMORY_SCOPE_AGENT);
    old = __shfl(old, 0);
    if (old == NBLK - 1) {
      __builtin_amdgcn_fence(__ATOMIC_ACQUIRE, "agent");
      float t = __hip_atomic_load(&wsf[WS_ACCB + lane * 16],
                                  __ATOMIC_RELAXED, __HIP_MEMORY_SCOPE_AGENT);
      #pragma unroll
      for (int off = 32; off; off >>= 1) t += __shfl_down(t, off);
      if (lane == 0) out[0] = t * wsf[WS_SL];
    }
  }
}

extern "C" void kernel_launch(void* const* d_in, const int* in_sizes, int n_in,
                              void* d_out, int out_size, void* d_ws, size_t ws_size,
                              hipStream_t stream) {
  const float* src    = (const float*)d_in[0];
  const float* tgt    = (const float*)d_in[1];
  const int*   label  = (const int*)d_in[2];
  const float* logits = (const float*)d_in[3];
  const int*   iter_p = (const int*)d_in[4];
  float* wsf = (float*)d_ws;
  unsigned short* Xc = (unsigned short*)((char*)d_ws + WS_XC_BYTES);
  float* out = (float*)d_out;

  hipMemsetAsync(d_ws, 0, 24576, stream);   // zero scalars/counters/buckets/stats
  k_pre<<<NPRE, 256, 0, stream>>>(src, tgt, label, logits, iter_p, wsf, Xc);
  k_main<<<NBLK, 256, 0, stream>>>(Xc, label, logits, wsf, out);
}